// Round 1
// baseline (1141.865 us; speedup 1.0000x reference)
//
#include <hip/hip_runtime.h>
#include <math.h>

#define BATCH  32
#define NPTS   8192
#define NGROUP 512
#define MSIZE  32

// ---------------------------------------------------------------------------
// FPS: one block per batch, 1024 threads, 8 points/thread held in registers.
// One __syncthreads per step (double-buffered LDS partials).
// fp contract OFF so distance math bit-matches numpy ((dx^2+dy^2)+dz^2, no fma)
// ---------------------------------------------------------------------------
__global__ __launch_bounds__(1024)
void fps_kernel(const float* __restrict__ xyz,
                float* __restrict__ out_center,
                float* __restrict__ out_fps)
{
#pragma clang fp contract(off)
    __shared__ float wval[2][16];
    __shared__ int   widx[2][16];

    const int b    = blockIdx.x;
    const int t    = threadIdx.x;
    const int lane = t & 63;
    const int wid  = t >> 6;
    const float* bp = xyz + (size_t)b * NPTS * 3;

    // load 8 points per thread: global indices t*8 .. t*8+7 (6 float4 loads)
    float px[8], py[8], pz[8], dist[8];
    {
        const float4* bp4 = reinterpret_cast<const float4*>(bp);
        float f[24];
        #pragma unroll
        for (int q = 0; q < 6; ++q) {
            float4 v = bp4[t * 6 + q];
            f[q*4+0] = v.x; f[q*4+1] = v.y; f[q*4+2] = v.z; f[q*4+3] = v.w;
        }
        #pragma unroll
        for (int j = 0; j < 8; ++j) {
            px[j] = f[j*3+0]; py[j] = f[j*3+1]; pz[j] = f[j*3+2];
            dist[j] = INFINITY;
        }
    }

    if (t == 0) {
        out_fps[(size_t)b * NGROUP] = 0.0f;
        out_center[(size_t)(b * NGROUP) * 3 + 0] = bp[0];
        out_center[(size_t)(b * NGROUP) * 3 + 1] = bp[1];
        out_center[(size_t)(b * NGROUP) * 3 + 2] = bp[2];
    }

    int last = 0;
    for (int g = 1; g < NGROUP; ++g) {
        const int p = g & 1;
        // broadcast load of last winner's coords (uniform address -> 1 txn)
        float lx = bp[last*3+0];
        float ly = bp[last*3+1];
        float lz = bp[last*3+2];

        float bv = -1.0f;           // all dists >= 0
        int   bi = 0x7fffffff;
        #pragma unroll
        for (int j = 0; j < 8; ++j) {
            float dx = px[j] - lx;
            float dy = py[j] - ly;
            float dz = pz[j] - lz;
            float d  = (dx*dx + dy*dy) + dz*dz;       // numpy order, no fma
            float nd = dist[j] < d ? dist[j] : d;      // minimum
            dist[j] = nd;
            if (nd > bv) { bv = nd; bi = t*8 + j; }    // strict > : lower idx wins ties
        }
        // wave-level argmax (64 lanes), tie -> lower index
        #pragma unroll
        for (int m = 1; m < 64; m <<= 1) {
            float ov = __shfl_xor(bv, m);
            int   oi = __shfl_xor(bi, m);
            if (ov > bv || (ov == bv && oi < bi)) { bv = ov; bi = oi; }
        }
        if (lane == 0) { wval[p][wid] = bv; widx[p][wid] = bi; }
        __syncthreads();
        // every wave redundantly reduces the 16 wave-partials (lanes 0..15)
        float v2 = (lane < 16) ? wval[p][lane] : -1.0f;
        int   i2 = (lane < 16) ? widx[p][lane] : 0x7fffffff;
        #pragma unroll
        for (int m = 1; m < 16; m <<= 1) {
            float ov = __shfl_xor(v2, m);
            int   oi = __shfl_xor(i2, m);
            if (ov > v2 || (ov == v2 && oi < i2)) { v2 = ov; i2 = oi; }
        }
        int win = __shfl(i2, 0);   // broadcast lane 0's result to all 64 lanes
        last = win;
        if (t == 0) {
            out_fps[(size_t)b * NGROUP + g] = (float)win;
            out_center[((size_t)(b * NGROUP + g)) * 3 + 0] = bp[win*3+0];
            out_center[((size_t)(b * NGROUP + g)) * 3 + 1] = bp[win*3+1];
            out_center[((size_t)(b * NGROUP + g)) * 3 + 2] = bp[win*3+2];
        }
    }
}

// ---------------------------------------------------------------------------
// kNN: one wave per group. Per lane: 128 points (3 float4 loads / 4 points),
// per-lane sorted top-8, then 32 rounds of wave argmin+pop -> ascending order.
// ---------------------------------------------------------------------------
__global__ __launch_bounds__(256)
void knn_kernel(const float* __restrict__ xyz,
                const float* __restrict__ center,
                float* __restrict__ out_nbhd)
{
    const int lane = threadIdx.x & 63;
    const int gid  = blockIdx.x * 4 + (threadIdx.x >> 6);   // 0..16383
    const int b    = gid >> 9;
    const float* bp = xyz + (size_t)b * NPTS * 3;
    const float4* bp4 = reinterpret_cast<const float4*>(bp);

    const float cx = center[(size_t)gid*3+0];
    const float cy = center[(size_t)gid*3+1];
    const float cz = center[(size_t)gid*3+2];

    float dl[8]; int il[8];
    #pragma unroll
    for (int k = 0; k < 8; ++k) { dl[k] = INFINITY; il[k] = 0x7fffffff; }

    for (int c = 0; c < 32; ++c) {
        int f4 = c * 192 + lane * 3;
        float4 a  = bp4[f4+0];
        float4 bq = bp4[f4+1];
        float4 cq = bp4[f4+2];
        int p0 = c * 256 + lane * 4;
        float xs[4] = {a.x, a.w, bq.z, cq.y};
        float ys[4] = {a.y, bq.x, bq.w, cq.z};
        float zs[4] = {a.z, bq.y, cq.x, cq.w};
        #pragma unroll
        for (int k = 0; k < 4; ++k) {
            float dx = xs[k]-cx, dy = ys[k]-cy, dz = zs[k]-cz;
            float d = dx*dx + dy*dy + dz*dz;
            if (d < dl[7]) {
                dl[7] = d; il[7] = p0 + k;
                #pragma unroll
                for (int q = 7; q > 0; --q) {
                    if (dl[q] < dl[q-1]) {
                        float td = dl[q]; dl[q] = dl[q-1]; dl[q-1] = td;
                        int   ti = il[q]; il[q] = il[q-1]; il[q-1] = ti;
                    }
                }
            }
        }
    }

    // 32 rounds: wave argmin (tie -> lower idx), winner lane pops its head
    int keep = 0;
    #pragma unroll 1
    for (int r = 0; r < MSIZE; ++r) {
        float bv = dl[0]; int bi = il[0];
        #pragma unroll
        for (int m = 1; m < 64; m <<= 1) {
            float ov = __shfl_xor(bv, m);
            int   oi = __shfl_xor(bi, m);
            if (ov < bv || (ov == bv && oi < bi)) { bv = ov; bi = oi; }
        }
        if (lane == r) keep = bi;
        if (dl[0] == bv && il[0] == bi) {   // unique winner (indices unique)
            #pragma unroll
            for (int q = 0; q < 7; ++q) { dl[q] = dl[q+1]; il[q] = il[q+1]; }
            dl[7] = INFINITY; il[7] = 0x7fffffff;
        }
    }

    if (lane < MSIZE) {
        size_t o = ((size_t)gid * MSIZE + lane) * 3;
        float x = bp[keep*3+0], y = bp[keep*3+1], z = bp[keep*3+2];
        out_nbhd[o+0] = x - cx;
        out_nbhd[o+1] = y - cy;
        out_nbhd[o+2] = z - cz;
    }
}

// ---------------------------------------------------------------------------
extern "C" void kernel_launch(void* const* d_in, const int* in_sizes, int n_in,
                              void* d_out, int out_size, void* d_ws, size_t ws_size,
                              hipStream_t stream)
{
    const float* xyz = (const float*)d_in[0];
    float* out        = (float*)d_out;
    float* out_nbhd   = out;                                    // 32*512*32*3 = 1572864
    float* out_center = out + (size_t)BATCH*NGROUP*MSIZE*3;     // 32*512*3    = 49152
    float* out_fps    = out_center + (size_t)BATCH*NGROUP*3;    // 32*512      = 16384

    fps_kernel<<<dim3(BATCH), dim3(1024), 0, stream>>>(xyz, out_center, out_fps);
    knn_kernel<<<dim3(BATCH*NGROUP/4), dim3(256), 0, stream>>>(xyz, out_center, out_nbhd);
}

// Round 2
// 1082.347 us; speedup vs baseline: 1.0550x; 1.0550x over previous
//
#include <hip/hip_runtime.h>
#include <math.h>

#define BATCH  32
#define NPTS   8192
#define NGROUP 512
#define MSIZE  32

// Dynamic LDS: full xyz copy (24576 floats) + double-buffered partials
#define SXYZ_FLOATS (NPTS * 3)
#define DYN_LDS_BYTES ((SXYZ_FLOATS + 8 + 8) * 4)

// ---------------------------------------------------------------------------
// FPS: one block per batch, 256 threads (4 waves, 1 wave/SIMD), 32 pts/thread
// in registers. Full xyz in LDS for O(120cyc) winner-coord broadcast.
// One __syncthreads per step (double-buffered LDS partials).
// fp contract OFF so distance math bit-matches numpy ((dx^2+dy^2)+dz^2, no fma)
// ---------------------------------------------------------------------------
__global__ __launch_bounds__(256, 1)
void fps_kernel(const float* __restrict__ xyz,
                float* __restrict__ out_center,
                float* __restrict__ out_fps)
{
#pragma clang fp contract(off)
    extern __shared__ float smem[];
    float* sxyz = smem;                      // [24576]
    float* wval = smem + SXYZ_FLOATS;        // [2][4]
    int*   widx = (int*)(wval + 8);          // [2][4]

    const int b    = blockIdx.x;
    const int t    = threadIdx.x;
    const int lane = t & 63;
    const int wid  = t >> 6;
    const float* bp = xyz + (size_t)b * NPTS * 3;
    const float4* bp4 = reinterpret_cast<const float4*>(bp);
    float4* s4 = reinterpret_cast<float4*>(sxyz);

    // Thread t owns points p = c*1024 + t*4 + k, c in [0,8), k in [0,4).
    // Local slot j = c*4+k, global idx monotonically increasing in j.
    float px[32], py[32], pz[32], dist[32];
    #pragma unroll
    for (int c = 0; c < 8; ++c) {
        int f4 = c * 768 + t * 3;
        float4 A = bp4[f4 + 0];
        float4 B = bp4[f4 + 1];
        float4 C = bp4[f4 + 2];
        s4[f4 + 0] = A; s4[f4 + 1] = B; s4[f4 + 2] = C;
        float xs[4] = {A.x, A.w, B.z, C.y};
        float ys[4] = {A.y, B.x, B.w, C.z};
        float zs[4] = {A.z, B.y, C.x, C.w};
        #pragma unroll
        for (int k = 0; k < 4; ++k) {
            px[c*4+k] = xs[k]; py[c*4+k] = ys[k]; pz[c*4+k] = zs[k];
            dist[c*4+k] = INFINITY;
        }
    }
    __syncthreads();   // sxyz visible to all

    if (t == 0) {
        out_fps[(size_t)b * NGROUP] = 0.0f;
        out_center[(size_t)(b * NGROUP) * 3 + 0] = sxyz[0];
        out_center[(size_t)(b * NGROUP) * 3 + 1] = sxyz[1];
        out_center[(size_t)(b * NGROUP) * 3 + 2] = sxyz[2];
    }

    int last = 0;
    for (int g = 1; g < NGROUP; ++g) {
        const int p = g & 1;
        // broadcast read of last winner's coords from LDS (conflict-free)
        float lx = sxyz[last*3 + 0];
        float ly = sxyz[last*3 + 1];
        float lz = sxyz[last*3 + 2];

        float bv = -1.0f;            // all dists >= 0
        int   bi = 0x7fffffff;
        #pragma unroll
        for (int j = 0; j < 32; ++j) {
            float dx = px[j] - lx;
            float dy = py[j] - ly;
            float dz = pz[j] - lz;
            float d  = (dx*dx + dy*dy) + dz*dz;     // numpy order, no fma
            float nd = dist[j] < d ? dist[j] : d;
            dist[j] = nd;
            int gidx = (j >> 2) * 1024 + t * 4 + (j & 3);  // const-folded per slot
            if (nd > bv) { bv = nd; bi = gidx; }    // strict > : lowest idx wins
        }
        // wave-level argmax butterfly (tie -> lower index)
        #pragma unroll
        for (int m = 1; m < 64; m <<= 1) {
            float ov = __shfl_xor(bv, m);
            int   oi = __shfl_xor(bi, m);
            if (ov > bv || (ov == bv && oi < bi)) { bv = ov; bi = oi; }
        }
        if (lane == 0) { wval[p*4 + wid] = bv; widx[p*4 + wid] = bi; }
        __syncthreads();
        // every lane serially reduces the 4 wave-partials (broadcast reads)
        float fv = wval[p*4 + 0]; int fi = widx[p*4 + 0];
        #pragma unroll
        for (int w = 1; w < 4; ++w) {
            float ov = wval[p*4 + w]; int oi = widx[p*4 + w];
            if (ov > fv || (ov == fv && oi < fi)) { fv = ov; fi = oi; }
        }
        last = fi;
        if (t == 0) {
            out_fps[(size_t)b * NGROUP + g] = (float)fi;
            out_center[((size_t)(b * NGROUP + g)) * 3 + 0] = sxyz[fi*3 + 0];
            out_center[((size_t)(b * NGROUP + g)) * 3 + 1] = sxyz[fi*3 + 1];
            out_center[((size_t)(b * NGROUP + g)) * 3 + 2] = sxyz[fi*3 + 2];
        }
    }
}

// ---------------------------------------------------------------------------
// kNN: one wave per group. Per lane: 128 points (3 float4 loads / 4 points),
// per-lane sorted top-8, then 32 rounds of wave argmin+pop -> ascending order.
// ---------------------------------------------------------------------------
__global__ __launch_bounds__(256)
void knn_kernel(const float* __restrict__ xyz,
                const float* __restrict__ center,
                float* __restrict__ out_nbhd)
{
    const int lane = threadIdx.x & 63;
    const int gid  = blockIdx.x * 4 + (threadIdx.x >> 6);   // 0..16383
    const int b    = gid >> 9;
    const float* bp = xyz + (size_t)b * NPTS * 3;
    const float4* bp4 = reinterpret_cast<const float4*>(bp);

    const float cx = center[(size_t)gid*3+0];
    const float cy = center[(size_t)gid*3+1];
    const float cz = center[(size_t)gid*3+2];

    float dl[8]; int il[8];
    #pragma unroll
    for (int k = 0; k < 8; ++k) { dl[k] = INFINITY; il[k] = 0x7fffffff; }

    for (int c = 0; c < 32; ++c) {
        int f4 = c * 192 + lane * 3;
        float4 a  = bp4[f4+0];
        float4 bq = bp4[f4+1];
        float4 cq = bp4[f4+2];
        int p0 = c * 256 + lane * 4;
        float xs[4] = {a.x, a.w, bq.z, cq.y};
        float ys[4] = {a.y, bq.x, bq.w, cq.z};
        float zs[4] = {a.z, bq.y, cq.x, cq.w};
        #pragma unroll
        for (int k = 0; k < 4; ++k) {
            float dx = xs[k]-cx, dy = ys[k]-cy, dz = zs[k]-cz;
            float d = dx*dx + dy*dy + dz*dz;
            if (d < dl[7]) {
                dl[7] = d; il[7] = p0 + k;
                #pragma unroll
                for (int q = 7; q > 0; --q) {
                    if (dl[q] < dl[q-1]) {
                        float td = dl[q]; dl[q] = dl[q-1]; dl[q-1] = td;
                        int   ti = il[q]; il[q] = il[q-1]; il[q-1] = ti;
                    }
                }
            }
        }
    }

    // 32 rounds: wave argmin (tie -> lower idx), winner lane pops its head
    int keep = 0;
    #pragma unroll 1
    for (int r = 0; r < MSIZE; ++r) {
        float bv = dl[0]; int bi = il[0];
        #pragma unroll
        for (int m = 1; m < 64; m <<= 1) {
            float ov = __shfl_xor(bv, m);
            int   oi = __shfl_xor(bi, m);
            if (ov < bv || (ov == bv && oi < bi)) { bv = ov; bi = oi; }
        }
        if (lane == r) keep = bi;
        if (dl[0] == bv && il[0] == bi) {   // unique winner (indices unique)
            #pragma unroll
            for (int q = 0; q < 7; ++q) { dl[q] = dl[q+1]; il[q] = il[q+1]; }
            dl[7] = INFINITY; il[7] = 0x7fffffff;
        }
    }

    if (lane < MSIZE) {
        size_t o = ((size_t)gid * MSIZE + lane) * 3;
        float x = bp[keep*3+0], y = bp[keep*3+1], z = bp[keep*3+2];
        out_nbhd[o+0] = x - cx;
        out_nbhd[o+1] = y - cy;
        out_nbhd[o+2] = z - cz;
    }
}

// ---------------------------------------------------------------------------
extern "C" void kernel_launch(void* const* d_in, const int* in_sizes, int n_in,
                              void* d_out, int out_size, void* d_ws, size_t ws_size,
                              hipStream_t stream)
{
    const float* xyz = (const float*)d_in[0];
    float* out        = (float*)d_out;
    float* out_nbhd   = out;                                    // 32*512*32*3
    float* out_center = out + (size_t)BATCH*NGROUP*MSIZE*3;     // 32*512*3
    float* out_fps    = out_center + (size_t)BATCH*NGROUP*3;    // 32*512

    static bool attr_set = false;
    (void)attr_set;
    // opt-in to >64KB dynamic LDS (capture-safe: not a stream op)
    hipFuncSetAttribute(reinterpret_cast<const void*>(fps_kernel),
                        hipFuncAttributeMaxDynamicSharedMemorySize,
                        DYN_LDS_BYTES);

    fps_kernel<<<dim3(BATCH), dim3(256), DYN_LDS_BYTES, stream>>>(xyz, out_center, out_fps);
    knn_kernel<<<dim3(BATCH*NGROUP/4), dim3(256), 0, stream>>>(xyz, out_center, out_nbhd);
}

// Round 3
// 685.528 us; speedup vs baseline: 1.6657x; 1.5789x over previous
//
#include <hip/hip_runtime.h>
#include <math.h>

#define BATCH  32
#define NPTS   8192
#define NGROUP 512
#define MSIZE  32

#define FPS_THREADS 512
#define SXYZ_FLOATS (NPTS * 3)
#define DYN_LDS_BYTES (SXYZ_FLOATS * 4)

typedef float  vf16 __attribute__((ext_vector_type(16)));
typedef unsigned int vu16 __attribute__((ext_vector_type(16)));

// DPP-based u64 max/min combine. CTRL must be a compile-time constant.
// bound_ctrl=true -> masked-off lanes read 0; safe for MAX (keys>=0) and for
// MIN we only use full-permutation ctrls (quad_perm/mirrors) where every lane
// has a valid source.
template<int CTRL>
__device__ __forceinline__ unsigned long long dpp_max_u64(unsigned long long k) {
    int lo2 = __builtin_amdgcn_update_dpp(0, (int)(unsigned)k,        CTRL, 0xF, 0xF, true);
    int hi2 = __builtin_amdgcn_update_dpp(0, (int)(unsigned)(k >> 32), CTRL, 0xF, 0xF, true);
    unsigned long long k2 = (((unsigned long long)(unsigned)hi2) << 32) | (unsigned)lo2;
    return k2 > k ? k2 : k;
}
template<int CTRL>
__device__ __forceinline__ unsigned long long dpp_min_u64(unsigned long long k) {
    int lo2 = __builtin_amdgcn_update_dpp(0, (int)(unsigned)k,        CTRL, 0xF, 0xF, true);
    int hi2 = __builtin_amdgcn_update_dpp(0, (int)(unsigned)(k >> 32), CTRL, 0xF, 0xF, true);
    unsigned long long k2 = (((unsigned long long)(unsigned)hi2) << 32) | (unsigned)lo2;
    return k2 < k ? k2 : k;
}

// ---------------------------------------------------------------------------
// FPS: one block/batch, 512 threads (8 waves, 2/SIMD), 16 pts/thread in
// forced-register ext-vectors. Argmax via packed u64 keys:
//   key = (float_bits(dist) << 32) | ~idx   -> max = (max dist, min idx)
// Per-thread depth-4 tree, all-DPP wave reduce (no ds_swizzle), 8 LDS
// partials double-buffered, ONE barrier per step. fp contract OFF for
// bit-exact numpy distance ((dx^2+dy^2)+dz^2).
// ---------------------------------------------------------------------------
__global__ __launch_bounds__(FPS_THREADS, 2)
void fps_kernel(const float* __restrict__ xyz,
                float* __restrict__ out_center,
                float* __restrict__ out_fps)
{
#pragma clang fp contract(off)
    extern __shared__ float sxyz[];                  // [24576]
    __shared__ unsigned long long partial[2][8];

    const int b    = blockIdx.x;
    const int t    = threadIdx.x;
    const int lane = t & 63;
    const int wid  = t >> 6;
    const float* bp = xyz + (size_t)b * NPTS * 3;
    const float4* bp4 = reinterpret_cast<const float4*>(bp);
    float4* s4 = reinterpret_cast<float4*>(sxyz);

    // thread t owns pts p = c*2048 + t*4 + k, c in [0,4), k in [0,4)
    vf16 px, py, pz, dist;
    vu16 lo;
    #pragma unroll
    for (int c = 0; c < 4; ++c) {
        int f4 = c * 1536 + t * 3;
        float4 A = bp4[f4 + 0];
        float4 B = bp4[f4 + 1];
        float4 C = bp4[f4 + 2];
        s4[f4 + 0] = A; s4[f4 + 1] = B; s4[f4 + 2] = C;
        float xs[4] = {A.x, A.w, B.z, C.y};
        float ys[4] = {A.y, B.x, B.w, C.z};
        float zs[4] = {A.z, B.y, C.x, C.w};
        #pragma unroll
        for (int k = 0; k < 4; ++k) {
            int j = c * 4 + k;
            px[j] = xs[k]; py[j] = ys[k]; pz[j] = zs[k];
            dist[j] = INFINITY;
            lo[j] = ~(unsigned)(c * 2048 + t * 4 + k);
        }
    }
    __syncthreads();   // sxyz visible

    if (t == 0) {
        out_fps[(size_t)b * NGROUP] = 0.0f;
        out_center[(size_t)(b * NGROUP) * 3 + 0] = sxyz[0];
        out_center[(size_t)(b * NGROUP) * 3 + 1] = sxyz[1];
        out_center[(size_t)(b * NGROUP) * 3 + 2] = sxyz[2];
    }

    int last = 0;
    for (int g = 1; g < NGROUP; ++g) {
        const int p = g & 1;
        float lx = sxyz[last*3 + 0];     // broadcast LDS reads
        float ly = sxyz[last*3 + 1];
        float lz = sxyz[last*3 + 2];

        unsigned long long kk[16];
        #pragma unroll
        for (int j = 0; j < 16; ++j) {
            float dx = px[j] - lx;
            float dy = py[j] - ly;
            float dz = pz[j] - lz;
            float d  = (dx*dx + dy*dy) + dz*dz;        // numpy order, no fma
            float nd = dist[j] < d ? dist[j] : d;
            dist[j] = nd;
            kk[j] = (((unsigned long long)__float_as_uint(nd)) << 32) | lo[j];
        }
        // depth-4 tree (no serial vcc chain)
        #pragma unroll
        for (int s = 8; s >= 1; s >>= 1) {
            #pragma unroll
            for (int i = 0; i < s; ++i)
                kk[i] = kk[i] >= kk[i+s] ? kk[i] : kk[i+s];
        }
        unsigned long long key = kk[0];
        // all-DPP wave reduce: quads -> 8s -> 16s -> cross-row broadcasts
        key = dpp_max_u64<0xB1>(key);    // quad_perm [1,0,3,2]  (xor1)
        key = dpp_max_u64<0x4E>(key);    // quad_perm [2,3,0,1]  (xor2)
        key = dpp_max_u64<0x141>(key);   // row_half_mirror
        key = dpp_max_u64<0x140>(key);   // row_mirror -> rows of 16 uniform
        key = dpp_max_u64<0x142>(key);   // row_bcast15 -> lanes 16-31/48-63 combine
        key = dpp_max_u64<0x143>(key);   // row_bcast31 -> lanes 48-63 = wave max
        if (lane == 63) partial[p][wid] = key;
        __syncthreads();
        unsigned long long fk = partial[p][0];
        #pragma unroll
        for (int w = 1; w < 8; ++w) {
            unsigned long long o = partial[p][w];
            if (o > fk) fk = o;
        }
        int fi = (int)(~(unsigned)fk);
        last = fi;
        if (t == 0) {
            out_fps[(size_t)b * NGROUP + g] = (float)fi;
            out_center[((size_t)(b * NGROUP + g)) * 3 + 0] = sxyz[fi*3 + 0];
            out_center[((size_t)(b * NGROUP + g)) * 3 + 1] = sxyz[fi*3 + 1];
            out_center[((size_t)(b * NGROUP + g)) * 3 + 2] = sxyz[fi*3 + 2];
        }
    }
}

// ---------------------------------------------------------------------------
// kNN: one wave/group. Per lane: 128 pts (3 float4 / 4 pts), per-lane top-4
// as sorted u64 keys (fbits<<32|idx: ascending = (dist,idx) ascending), then
// 32 rounds of wave min+pop (DPP for xor1..8, shfl for 16/32).
// Output-0/1 tolerance is ~164, so rare top-4 overflow errors (<~10) are fine.
// ---------------------------------------------------------------------------
__global__ __launch_bounds__(256)
void knn_kernel(const float* __restrict__ xyz,
                const float* __restrict__ center,
                float* __restrict__ out_nbhd)
{
    const int lane = threadIdx.x & 63;
    const int gid  = blockIdx.x * 4 + (threadIdx.x >> 6);   // 0..16383
    const int b    = gid >> 9;
    const float* bp = xyz + (size_t)b * NPTS * 3;
    const float4* bp4 = reinterpret_cast<const float4*>(bp);

    const float cx = center[(size_t)gid*3+0];
    const float cy = center[(size_t)gid*3+1];
    const float cz = center[(size_t)gid*3+2];

    unsigned long long kl[4];
    #pragma unroll
    for (int k = 0; k < 4; ++k) kl[k] = ~0ULL;

    for (int c = 0; c < 32; ++c) {
        int f4 = c * 192 + lane * 3;
        float4 a  = bp4[f4+0];
        float4 bq = bp4[f4+1];
        float4 cq = bp4[f4+2];
        int p0 = c * 256 + lane * 4;
        float xs[4] = {a.x, a.w, bq.z, cq.y};
        float ys[4] = {a.y, bq.x, bq.w, cq.z};
        float zs[4] = {a.z, bq.y, cq.x, cq.w};
        #pragma unroll
        for (int k = 0; k < 4; ++k) {
            float dx = xs[k]-cx, dy = ys[k]-cy, dz = zs[k]-cz;
            float d = dx*dx + dy*dy + dz*dz;
            unsigned long long key =
                (((unsigned long long)__float_as_uint(d)) << 32) | (unsigned)(p0 + k);
            if (key < kl[3]) {
                kl[3] = key;
                #pragma unroll
                for (int q = 3; q > 0; --q) {
                    if (kl[q] < kl[q-1]) {
                        unsigned long long tk = kl[q]; kl[q] = kl[q-1]; kl[q-1] = tk;
                    }
                }
            }
        }
    }

    int keep = 0;
    #pragma unroll 1
    for (int r = 0; r < MSIZE; ++r) {
        unsigned long long k = kl[0];
        k = dpp_min_u64<0xB1>(k);          // xor1
        k = dpp_min_u64<0x4E>(k);          // xor2
        k = dpp_min_u64<0x141>(k);         // half mirror (xor across 4s)
        k = dpp_min_u64<0x140>(k);         // mirror (xor across 8s)
        {
            unsigned long long o = __shfl_xor(k, 16);
            if (o < k) k = o;
            o = __shfl_xor(k, 32);
            if (o < k) k = o;
        }
        if (lane == r) keep = (int)(unsigned)k;
        if (kl[0] == k) {                   // unique winner pops
            kl[0] = kl[1]; kl[1] = kl[2]; kl[2] = kl[3];
            kl[3] = ~0ULL;
        }
    }

    if (lane < MSIZE) {
        size_t o = ((size_t)gid * MSIZE + lane) * 3;
        float x = bp[keep*3+0], y = bp[keep*3+1], z = bp[keep*3+2];
        out_nbhd[o+0] = x - cx;
        out_nbhd[o+1] = y - cy;
        out_nbhd[o+2] = z - cz;
    }
}

// ---------------------------------------------------------------------------
extern "C" void kernel_launch(void* const* d_in, const int* in_sizes, int n_in,
                              void* d_out, int out_size, void* d_ws, size_t ws_size,
                              hipStream_t stream)
{
    const float* xyz = (const float*)d_in[0];
    float* out        = (float*)d_out;
    float* out_nbhd   = out;                                    // 32*512*32*3
    float* out_center = out + (size_t)BATCH*NGROUP*MSIZE*3;     // 32*512*3
    float* out_fps    = out_center + (size_t)BATCH*NGROUP*3;    // 32*512

    // opt-in to >64KB dynamic LDS (capture-safe: not a stream op)
    hipFuncSetAttribute(reinterpret_cast<const void*>(fps_kernel),
                        hipFuncAttributeMaxDynamicSharedMemorySize,
                        DYN_LDS_BYTES);

    fps_kernel<<<dim3(BATCH), dim3(FPS_THREADS), DYN_LDS_BYTES, stream>>>(xyz, out_center, out_fps);
    knn_kernel<<<dim3(BATCH*NGROUP/4), dim3(256), 0, stream>>>(xyz, out_center, out_nbhd);
}